// Round 1
// baseline (5053.452 us; speedup 1.0000x reference)
//
#include <hip/hip_runtime.h>

typedef __attribute__((ext_vector_type(8))) short bf16x8_t;
typedef __attribute__((ext_vector_type(4))) float f32x4_t;

__device__ __forceinline__ ushort f2bf(float x) {
  union { float f; unsigned u; } a; a.f = x;
  unsigned r = a.u + 0x7fffu + ((a.u >> 16) & 1u);
  return (ushort)(r >> 16);
}
__device__ __forceinline__ float bf2f(ushort s) {
  union { unsigned u; float f; } a; a.u = ((unsigned)s) << 16;
  return a.f;
}

// ---------------- weight conversion ----------------
__global__ void cvt_kernel(const float* __restrict__ s, ushort* __restrict__ d, int n) {
  int i = blockIdx.x * 256 + threadIdx.x;
  if (i < n) d[i] = f2bf(s[i]);
}

// Wcat[l][r][c], r: 0-63 A_w, 64-127 B_w, 128-383 gate_w, 384-639 D_w
__global__ void build_wcat(const float* __restrict__ Aw, const float* __restrict__ Bw,
                           const float* __restrict__ gw, const float* __restrict__ Dw,
                           ushort* __restrict__ out) {
  int i = blockIdx.x * 256 + threadIdx.x;
  if (i >= 6 * 640 * 256) return;
  int l = i / (640 * 256), r = (i / 256) % 640, c = i % 256;
  float v;
  if (r < 64)        v = Aw[((l * 64 + r) * 256) + c];
  else if (r < 128)  v = Bw[((l * 64 + (r - 64)) * 256) + c];
  else if (r < 384)  v = gw[((l * 256 + (r - 128)) * 256) + c];
  else               v = Dw[((l * 256 + (r - 384)) * 256) + c];
  out[i] = f2bf(v);
}

// ---------------- MFMA GEMM: out = epilogue(A[M,K] @ W[N,K]^T) ----------------
// MODE 0: fp32 out = v + b1[col]                      (input projection -> x)
// MODE 1: bf16 out, col<64 tanh | <128 id | <384 sigmoid(v+b1[col-128]) | else v+b2[col-384]
// MODE 2: bf16 out = gelu_exact(v + b1[col])          (ffn1 -> t)
// MODE 3: fp32 out[row,col] += v + b1[col]            (ffn2 residual add -> x)
template <int K, int MODE, bool AFP32>
__global__ __launch_bounds__(256)
void gemm_mfma(const void* __restrict__ Ap, const ushort* __restrict__ W,
               const float* __restrict__ b1, const float* __restrict__ b2,
               void* __restrict__ outp, int N) {
  __shared__ __align__(16) ushort As[128][40];
  __shared__ __align__(16) ushort Ws[128][40];

  const int t = threadIdx.x;
  const int lane = t & 63;
  const int wid = t >> 6;
  const long m0 = (long)blockIdx.x * 128;
  const int n0 = blockIdx.y * 128;
  const int wr = (wid >> 1) * 64;
  const int wc = (wid & 1) * 64;
  const int srow = t >> 1;
  const int scol = (t & 1) * 16;
  const int krow = lane & 15;
  const int kcol = (lane >> 4) * 8;

  const f32x4_t zero = {0.f, 0.f, 0.f, 0.f};
  f32x4_t acc[4][4];
#pragma unroll
  for (int i = 0; i < 4; ++i)
#pragma unroll
    for (int j = 0; j < 4; ++j) acc[i][j] = zero;

  for (int k0 = 0; k0 < K; k0 += 32) {
    if constexpr (AFP32) {
      const float* A = (const float*)Ap + (m0 + srow) * K + (k0 + scol);
      float4 q0 = ((const float4*)A)[0];
      float4 q1 = ((const float4*)A)[1];
      float4 q2 = ((const float4*)A)[2];
      float4 q3 = ((const float4*)A)[3];
      bf16x8_t v0, v1;
      v0[0] = (short)f2bf(q0.x); v0[1] = (short)f2bf(q0.y);
      v0[2] = (short)f2bf(q0.z); v0[3] = (short)f2bf(q0.w);
      v0[4] = (short)f2bf(q1.x); v0[5] = (short)f2bf(q1.y);
      v0[6] = (short)f2bf(q1.z); v0[7] = (short)f2bf(q1.w);
      v1[0] = (short)f2bf(q2.x); v1[1] = (short)f2bf(q2.y);
      v1[2] = (short)f2bf(q2.z); v1[3] = (short)f2bf(q2.w);
      v1[4] = (short)f2bf(q3.x); v1[5] = (short)f2bf(q3.y);
      v1[6] = (short)f2bf(q3.z); v1[7] = (short)f2bf(q3.w);
      *(bf16x8_t*)&As[srow][scol]     = v0;
      *(bf16x8_t*)&As[srow][scol + 8] = v1;
    } else {
      const ushort* A = (const ushort*)Ap + (m0 + srow) * K + (k0 + scol);
      *(bf16x8_t*)&As[srow][scol]     = *(const bf16x8_t*)A;
      *(bf16x8_t*)&As[srow][scol + 8] = *(const bf16x8_t*)(A + 8);
    }
    {
      const ushort* Wp = W + (long)(n0 + srow) * K + (k0 + scol);
      *(bf16x8_t*)&Ws[srow][scol]     = *(const bf16x8_t*)Wp;
      *(bf16x8_t*)&Ws[srow][scol + 8] = *(const bf16x8_t*)(Wp + 8);
    }
    __syncthreads();

    bf16x8_t af[4], bv[4];
#pragma unroll
    for (int i = 0; i < 4; ++i)
      af[i] = *(const bf16x8_t*)&As[wr + i * 16 + krow][kcol];
#pragma unroll
    for (int i = 0; i < 4; ++i)
      bv[i] = *(const bf16x8_t*)&Ws[wc + i * 16 + krow][kcol];

#pragma unroll
    for (int mi = 0; mi < 4; ++mi)
#pragma unroll
      for (int ni = 0; ni < 4; ++ni)
        acc[mi][ni] = __builtin_amdgcn_mfma_f32_16x16x32_bf16(af[mi], bv[ni], acc[mi][ni], 0, 0, 0);
    __syncthreads();
  }

  const int rbase = (lane >> 4) * 4;
  const int cbase = lane & 15;
#pragma unroll
  for (int mi = 0; mi < 4; ++mi) {
#pragma unroll
    for (int ni = 0; ni < 4; ++ni) {
      const int col = n0 + wc + ni * 16 + cbase;
#pragma unroll
      for (int j = 0; j < 4; ++j) {
        const long row = m0 + wr + mi * 16 + rbase + j;
        float v = acc[mi][ni][j];
        if constexpr (MODE == 0) {
          ((float*)outp)[row * N + col] = v + b1[col];
        } else if constexpr (MODE == 1) {
          float o;
          if (col < 64)       o = tanhf(v);
          else if (col < 128) o = v;
          else if (col < 384) { float s = v + b1[col - 128]; o = 1.f / (1.f + expf(-s)); }
          else                o = v + b2[col - 384];
          ((ushort*)outp)[row * N + col] = f2bf(o);
        } else if constexpr (MODE == 2) {
          float s = v + b1[col];
          float o = 0.5f * s * (1.f + erff(s * 0.70710678118654752f));
          ((ushort*)outp)[row * N + col] = f2bf(o);
        } else {
          ((float*)outp)[row * N + col] += v + b1[col];
        }
      }
    }
  }
}

// ---------------- LayerNorm: fp32 in -> bf16 out, one wave per 256-wide row ----------------
__global__ __launch_bounds__(256)
void ln_kernel(const float* __restrict__ x, const float* __restrict__ g,
               const float* __restrict__ b, ushort* __restrict__ y) {
  const int lane = threadIdx.x & 63;
  const long row = (long)blockIdx.x * 4 + (threadIdx.x >> 6);
  const float4 v = *(const float4*)(x + row * 256 + lane * 4);
  float s = v.x + v.y + v.z + v.w;
  float q = v.x * v.x + v.y * v.y + v.z * v.z + v.w * v.w;
#pragma unroll
  for (int off = 32; off > 0; off >>= 1) {
    s += __shfl_xor(s, off, 64);
    q += __shfl_xor(q, off, 64);
  }
  const float mean = s * (1.f / 256.f);
  const float rstd = rsqrtf(q * (1.f / 256.f) - mean * mean + 1e-5f);
  const int c = lane * 4;
  ushort4 o;
  o.x = f2bf((v.x - mean) * rstd * g[c + 0] + b[c + 0]);
  o.y = f2bf((v.y - mean) * rstd * g[c + 1] + b[c + 1]);
  o.z = f2bf((v.z - mean) * rstd * g[c + 2] + b[c + 2]);
  o.w = f2bf((v.w - mean) * rstd * g[c + 3] + b[c + 3]);
  *(ushort4*)(y + row * 256 + c) = o;
}

// ---------------- scan + C projection + gated combine, one block per batch ----------------
// z layout per token: [0:64]=a(tanh) [64:128]=bt [128:384]=g(sigmoid) [384:640]=dt
__global__ __launch_bounds__(256)
void scan_combine(const ushort* __restrict__ z, const float* __restrict__ Cw,
                  float* __restrict__ x) {
  __shared__ float hs[16][64];
  const int b = blockIdx.x;
  const int t = threadIdx.x;
  const ushort* zb = z + (long)b * 16 * 640;
  if (t < 64) {
    float h = 0.f;
    for (int s = 0; s < 16; ++s) {
      float a  = bf2f(zb[s * 640 + t]);
      float bt = bf2f(zb[s * 640 + 64 + t]);
      h = a * h + bt;
      hs[s][t] = h;
    }
  }
  __syncthreads();
  float c[64];
#pragma unroll
  for (int i = 0; i < 16; ++i) {
    float4 q = *(const float4*)(Cw + t * 64 + i * 4);
    c[4 * i + 0] = q.x; c[4 * i + 1] = q.y; c[4 * i + 2] = q.z; c[4 * i + 3] = q.w;
  }
  float* xb = x + (long)b * 16 * 256;
  for (int s = 0; s < 16; ++s) {
    float ys = 0.f;
#pragma unroll
    for (int d = 0; d < 64; ++d) ys += hs[s][d] * c[d];
    float gv = bf2f(zb[s * 640 + 128 + t]);
    float dv = bf2f(zb[s * 640 + 384 + t]);
    xb[s * 256 + t] += ys * gv + dv * (1.f - gv);
  }
}

// ---------------- head: final LN + neighbor attention + MLP + log_softmax ----------------
__global__ __launch_bounds__(256)
void head_kernel(const float* __restrict__ x, const float* __restrict__ fg,
                 const float* __restrict__ fb, const float* __restrict__ attw,
                 const float* __restrict__ attb, const float* __restrict__ ow,
                 const float* __restrict__ ob, const float* __restrict__ cw,
                 const float* __restrict__ cb, float* __restrict__ out) {
  __shared__ float xf[16][256];
  __shared__ float lg[16], aw[16];
  __shared__ float vs[256], o1[128], lgc[40], lse[1];
  const int t = threadIdx.x, lane = t & 63, wid = t >> 6;
  const float* xb = x + (long)blockIdx.x * 16 * 256;
  (void)attb;  // constant shift, cancels in softmax

  for (int r = wid; r < 16; r += 4) {
    float4 v = *(const float4*)(xb + r * 256 + lane * 4);
    float s = v.x + v.y + v.z + v.w;
    float q = v.x * v.x + v.y * v.y + v.z * v.z + v.w * v.w;
#pragma unroll
    for (int off = 32; off > 0; off >>= 1) {
      s += __shfl_xor(s, off, 64);
      q += __shfl_xor(q, off, 64);
    }
    float mean = s * (1.f / 256.f);
    float rstd = rsqrtf(q * (1.f / 256.f) - mean * mean + 1e-5f);
    int c = lane * 4;
    xf[r][c + 0] = (v.x - mean) * rstd * fg[c + 0] + fb[c + 0];
    xf[r][c + 1] = (v.y - mean) * rstd * fg[c + 1] + fb[c + 1];
    xf[r][c + 2] = (v.z - mean) * rstd * fg[c + 2] + fb[c + 2];
    xf[r][c + 3] = (v.w - mean) * rstd * fg[c + 3] + fb[c + 3];
  }
  __syncthreads();

  for (int r = wid; r < 16; r += 4) {
    const float* wv = attw + (r == 0 ? 0 : 256);
    int c = lane * 4;
    float s = xf[r][c] * wv[c] + xf[r][c + 1] * wv[c + 1] +
              xf[r][c + 2] * wv[c + 2] + xf[r][c + 3] * wv[c + 3];
#pragma unroll
    for (int off = 32; off > 0; off >>= 1) s += __shfl_xor(s, off, 64);
    if (lane == 0) lg[r] = s;
  }
  __syncthreads();

  if (t == 0) {
    float mx = -1e30f;
    for (int s2 = 1; s2 < 16; ++s2) mx = fmaxf(mx, lg[s2]);
    float den = 0.f;
    for (int s2 = 1; s2 < 16; ++s2) { float e = expf(lg[s2] - mx); aw[s2] = e; den += e; }
    float inv = 1.f / den;
    for (int s2 = 1; s2 < 16; ++s2) aw[s2] *= inv;
  }
  __syncthreads();

  float vh = xf[0][t];
  for (int s2 = 1; s2 < 16; ++s2) vh += aw[s2] * xf[s2][t];
  vs[t] = vh;
  __syncthreads();

  if (t < 128) {
    float s = ob[t];
    const float* w = ow + t * 256;
    for (int h2 = 0; h2 < 256; ++h2) s += w[h2] * vs[h2];
    o1[t] = fmaxf(s, 0.f);
  }
  __syncthreads();

  if (t < 40) {
    float s = cb[t];
    const float* w = cw + t * 128;
    for (int j = 0; j < 128; ++j) s += w[j] * o1[j];
    lgc[t] = s;
  }
  __syncthreads();

  if (t == 0) {
    float mx = -1e30f;
    for (int c2 = 0; c2 < 40; ++c2) mx = fmaxf(mx, lgc[c2]);
    float den = 0.f;
    for (int c2 = 0; c2 < 40; ++c2) den += expf(lgc[c2] - mx);
    lse[0] = mx + logf(den);
  }
  __syncthreads();
  if (t < 40) out[(long)blockIdx.x * 40 + t] = lgc[t] - lse[0];
}

// ---------------- host ----------------
extern "C" void kernel_launch(void* const* d_in, const int* in_sizes, int n_in,
                              void* d_out, int out_size, void* d_ws, size_t ws_size,
                              hipStream_t stream) {
  const float* data   = (const float*)d_in[0];
  const float* in_w   = (const float*)d_in[1];
  const float* in_b   = (const float*)d_in[2];
  const float* norm_g = (const float*)d_in[3];
  const float* norm_b = (const float*)d_in[4];
  const float* A_w    = (const float*)d_in[5];
  const float* B_w    = (const float*)d_in[6];
  const float* C_w    = (const float*)d_in[7];
  const float* D_w    = (const float*)d_in[8];
  const float* D_b    = (const float*)d_in[9];
  const float* gate_w = (const float*)d_in[10];
  const float* gate_b = (const float*)d_in[11];
  const float* ffn_w1 = (const float*)d_in[12];
  const float* ffn_b1 = (const float*)d_in[13];
  const float* ffn_w2 = (const float*)d_in[14];
  const float* ffn_b2 = (const float*)d_in[15];
  const float* fln_g  = (const float*)d_in[16];
  const float* fln_b  = (const float*)d_in[17];
  const float* out_w  = (const float*)d_in[18];
  const float* out_b  = (const float*)d_in[19];
  const float* cls_w  = (const float*)d_in[20];
  const float* cls_b  = (const float*)d_in[21];
  const float* attn_w = (const float*)d_in[22];
  const float* attn_b = (const float*)d_in[23];
  (void)in_sizes; (void)n_in; (void)out_size; (void)ws_size;

  char* ws = (char*)d_ws;
  float*  x    = (float*)(ws + 0);            // 131072*256*4  = 134217728
  ushort* y    = (ushort*)(ws + 134217728);   // 131072*256*2  =  67108864
  ushort* z    = (ushort*)(ws + 201326592);   // 131072*640*2  = 167772160 (reused as ffn1 out t)
  ushort* wcat = (ushort*)(ws + 369098752);   // 6*640*256*2   =   1966080
  ushort* inwb = (ushort*)(ws + 371064832);   // 256*512*2     =    262144
  ushort* w1b  = (ushort*)(ws + 371326976);   // 6*512*256*2   =   1572864
  ushort* w2b  = (ushort*)(ws + 372899840);   // 6*256*512*2   =   1572864

  cvt_kernel<<<(131072 + 255) / 256, 256, 0, stream>>>(in_w, inwb, 131072);
  cvt_kernel<<<(786432 + 255) / 256, 256, 0, stream>>>(ffn_w1, w1b, 786432);
  cvt_kernel<<<(786432 + 255) / 256, 256, 0, stream>>>(ffn_w2, w2b, 786432);
  build_wcat<<<(983040 + 255) / 256, 256, 0, stream>>>(A_w, B_w, gate_w, D_w, wcat);

  // x = data @ in_w^T + in_b   (M=131072, K=512, N=256)
  gemm_mfma<512, 0, true><<<dim3(1024, 2), 256, 0, stream>>>(data, inwb, in_b, nullptr, x, 256);

  for (int l = 0; l < 6; ++l) {
    ln_kernel<<<32768, 256, 0, stream>>>(x, norm_g + l * 256, norm_b + l * 256, y);
    gemm_mfma<256, 1, false><<<dim3(1024, 5), 256, 0, stream>>>(
        y, wcat + (size_t)l * 640 * 256, gate_b + l * 256, D_b + l * 256, z, 640);
    scan_combine<<<8192, 256, 0, stream>>>(z, C_w + (size_t)l * 256 * 64, x);
    ln_kernel<<<32768, 256, 0, stream>>>(x, norm_g + l * 256, norm_b + l * 256, y);
    gemm_mfma<256, 2, false><<<dim3(1024, 4), 256, 0, stream>>>(
        y, w1b + (size_t)l * 512 * 256, ffn_b1 + l * 512, nullptr, z, 512);
    gemm_mfma<512, 3, false><<<dim3(1024, 2), 256, 0, stream>>>(
        z, w2b + (size_t)l * 256 * 512, ffn_b2 + l * 256, nullptr, x, 256);
  }

  head_kernel<<<8192, 256, 0, stream>>>(x, fln_g, fln_b, attn_w, attn_b,
                                        out_w, out_b, cls_w, cls_b, (float*)d_out);
}

// Round 2
// 4188.802 us; speedup vs baseline: 1.2064x; 1.2064x over previous
//
#include <hip/hip_runtime.h>

typedef __attribute__((ext_vector_type(8))) short bf16x8_t;
typedef __attribute__((ext_vector_type(4))) float f32x4_t;

__device__ __forceinline__ ushort f2bf(float x) {
  union { float f; unsigned u; } a; a.f = x;
  unsigned r = a.u + 0x7fffu + ((a.u >> 16) & 1u);
  return (ushort)(r >> 16);
}
__device__ __forceinline__ float bf2f(ushort s) {
  union { unsigned u; float f; } a; a.u = ((unsigned)s) << 16;
  return a.f;
}

__device__ __forceinline__ void gload_lds16(const void* g, void* l) {
  __builtin_amdgcn_global_load_lds(
      (const __attribute__((address_space(1))) unsigned int*)g,
      (__attribute__((address_space(3))) unsigned int*)l, 16, 0, 0);
}

// ---------------- weight conversion ----------------
__global__ void cvt_kernel(const float* __restrict__ s, ushort* __restrict__ d, int n) {
  int i = blockIdx.x * 256 + threadIdx.x;
  if (i < n) d[i] = f2bf(s[i]);
}

__global__ void cvt4_kernel(const float* __restrict__ s, ushort* __restrict__ d, long n4) {
  long i = (long)blockIdx.x * 256 + threadIdx.x;
  if (i < n4) {
    float4 v = ((const float4*)s)[i];
    ushort4 o;
    o.x = f2bf(v.x); o.y = f2bf(v.y); o.z = f2bf(v.z); o.w = f2bf(v.w);
    ((ushort4*)d)[i] = o;
  }
}

// Wcat[l][r][c], r: 0-63 A_w, 64-127 B_w, 128-383 gate_w, 384-639 D_w
__global__ void build_wcat(const float* __restrict__ Aw, const float* __restrict__ Bw,
                           const float* __restrict__ gw, const float* __restrict__ Dw,
                           ushort* __restrict__ out) {
  int i = blockIdx.x * 256 + threadIdx.x;
  if (i >= 6 * 640 * 256) return;
  int l = i / (640 * 256), r = (i / 256) % 640, c = i % 256;
  float v;
  if (r < 64)        v = Aw[((l * 64 + r) * 256) + c];
  else if (r < 128)  v = Bw[((l * 64 + (r - 64)) * 256) + c];
  else if (r < 384)  v = gw[((l * 256 + (r - 128)) * 256) + c];
  else               v = Dw[((l * 256 + (r - 384)) * 256) + c];
  out[i] = f2bf(v);
}

// ---------------- MFMA GEMM (m97 structure): out = epi(A[M,K]bf16 @ W[N,K]bf16^T) --------
// LDS: linear [128][32] ushort per operand, XOR-swizzled (key = ((row>>2)^row)&3 on 16B slot)
// applied identically on the pre-swizzled global source and on the ds_read address.
// MODE 0: fp32 out = v + b1[col]                       (input projection -> x)
// MODE 1: bf16 out, col<64 tanh | <128 id | <384 sigmoid(v+b1[col-128]) | else v+b2[col-384]
// MODE 2: bf16 out = gelu_exact(v + b1[col])           (ffn1 -> t)
// MODE 3: fp32 out[row,col] += v + b1[col]             (ffn2 residual add -> x)
// MODE 4: fp32 out[row,col] += v*g + dt*(1-g), g/dt from zgd (scan C-mix combine -> x)
template <int K, int MODE>
__global__ __launch_bounds__(256)
void gemm_bf16(const ushort* __restrict__ A, const ushort* __restrict__ W,
               const float* __restrict__ b1, const float* __restrict__ b2,
               const ushort* __restrict__ zgd, void* __restrict__ outp, int N) {
  __shared__ __align__(16) ushort As[128 * 32];
  __shared__ __align__(16) ushort Ws[128 * 32];

  const int t = threadIdx.x;
  const int lane = t & 63;
  const int wid = t >> 6;
  const long m0 = (long)blockIdx.x * 128;
  const int n0 = blockIdx.y * 128;
  const int wr = (wid >> 1) * 64;
  const int wc = (wid & 1) * 64;

  // staging: 8 chunks of 16 rows x 64B per operand; wave w owns chunks {2w, 2w+1}
  const int c0 = wid * 2;
  const int r0 = c0 * 16 + (lane >> 2);
  const int r1 = r0 + 16;
  const int key0 = ((r0 >> 2) ^ r0) & 3;
  const int key1 = ((r1 >> 2) ^ r1) & 3;
  const int cb0 = ((lane & 3) << 4) ^ (key0 << 4);
  const int cb1 = ((lane & 3) << 4) ^ (key1 << 4);
  const char* Ab = (const char*)A;
  const char* Wb = (const char*)W;
  const long aro0 = (m0 + r0) * (long)K * 2;
  const long aro1 = (m0 + r1) * (long)K * 2;
  const long wro0 = (long)(n0 + r0) * K * 2;
  const long wro1 = (long)(n0 + r1) * K * 2;
  char* AsD0 = (char*)As + c0 * 1024;
  char* AsD1 = AsD0 + 1024;
  char* WsD0 = (char*)Ws + c0 * 1024;
  char* WsD1 = WsD0 + 1024;

  // fragment ds_read byte offsets (swizzled), constant per thread
  const int krow = lane & 15, kslot = lane >> 4;
  int aoff[4], boff[4];
#pragma unroll
  for (int i = 0; i < 4; ++i) {
    int ar = wr + i * 16 + krow;
    aoff[i] = ar * 64 + ((kslot ^ (((ar >> 2) ^ ar) & 3)) << 4);
    int br = wc + i * 16 + krow;
    boff[i] = br * 64 + ((kslot ^ (((br >> 2) ^ br) & 3)) << 4);
  }

  const f32x4_t zero = {0.f, 0.f, 0.f, 0.f};
  f32x4_t acc[4][4];
#pragma unroll
  for (int i = 0; i < 4; ++i)
#pragma unroll
    for (int j = 0; j < 4; ++j) acc[i][j] = zero;

  for (int k0 = 0; k0 < K; k0 += 32) {
    const long kb = (long)k0 * 2;
    gload_lds16(Ab + aro0 + kb + cb0, AsD0);
    gload_lds16(Ab + aro1 + kb + cb1, AsD1);
    gload_lds16(Wb + wro0 + kb + cb0, WsD0);
    gload_lds16(Wb + wro1 + kb + cb1, WsD1);
    __syncthreads();

    bf16x8_t af[4], bv[4];
#pragma unroll
    for (int i = 0; i < 4; ++i) af[i] = *(const bf16x8_t*)((const char*)As + aoff[i]);
#pragma unroll
    for (int i = 0; i < 4; ++i) bv[i] = *(const bf16x8_t*)((const char*)Ws + boff[i]);

#pragma unroll
    for (int mi = 0; mi < 4; ++mi)
#pragma unroll
      for (int ni = 0; ni < 4; ++ni)
        acc[mi][ni] = __builtin_amdgcn_mfma_f32_16x16x32_bf16(af[mi], bv[ni], acc[mi][ni], 0, 0, 0);
    __syncthreads();
  }

  const int rbase = (lane >> 4) * 4;
  const int cbase = lane & 15;
#pragma unroll
  for (int mi = 0; mi < 4; ++mi) {
#pragma unroll
    for (int ni = 0; ni < 4; ++ni) {
      const int col = n0 + wc + ni * 16 + cbase;
#pragma unroll
      for (int j = 0; j < 4; ++j) {
        const long row = m0 + wr + mi * 16 + rbase + j;
        float v = acc[mi][ni][j];
        if constexpr (MODE == 0) {
          ((float*)outp)[row * N + col] = v + b1[col];
        } else if constexpr (MODE == 1) {
          float o;
          if (col < 64)       o = tanhf(v);
          else if (col < 128) o = v;
          else if (col < 384) { float s = v + b1[col - 128]; o = 1.f / (1.f + expf(-s)); }
          else                o = v + b2[col - 384];
          ((ushort*)outp)[row * N + col] = f2bf(o);
        } else if constexpr (MODE == 2) {
          float s = v + b1[col];
          float o = 0.5f * s * (1.f + erff(s * 0.70710678118654752f));
          ((ushort*)outp)[row * N + col] = f2bf(o);
        } else if constexpr (MODE == 3) {
          ((float*)outp)[row * N + col] += v + b1[col];
        } else {
          float gv = bf2f(zgd[row * 640 + 128 + col]);
          float dv = bf2f(zgd[row * 640 + 384 + col]);
          ((float*)outp)[row * N + col] += v * gv + dv * (1.f - gv);
        }
      }
    }
  }
}

// ---------------- LayerNorm: fp32 in -> bf16 out, one wave per 256-wide row ----------------
__global__ __launch_bounds__(256)
void ln_kernel(const float* __restrict__ x, const float* __restrict__ g,
               const float* __restrict__ b, ushort* __restrict__ y) {
  const int lane = threadIdx.x & 63;
  const long row = (long)blockIdx.x * 4 + (threadIdx.x >> 6);
  const float4 v = *(const float4*)(x + row * 256 + lane * 4);
  float s = v.x + v.y + v.z + v.w;
  float q = v.x * v.x + v.y * v.y + v.z * v.z + v.w * v.w;
#pragma unroll
  for (int off = 32; off > 0; off >>= 1) {
    s += __shfl_xor(s, off, 64);
    q += __shfl_xor(q, off, 64);
  }
  const float mean = s * (1.f / 256.f);
  const float rstd = rsqrtf(q * (1.f / 256.f) - mean * mean + 1e-5f);
  const int c = lane * 4;
  const float4 gv = *(const float4*)(g + c);
  const float4 bv = *(const float4*)(b + c);
  ushort4 o;
  o.x = f2bf((v.x - mean) * rstd * gv.x + bv.x);
  o.y = f2bf((v.y - mean) * rstd * gv.y + bv.y);
  o.z = f2bf((v.z - mean) * rstd * gv.z + bv.z);
  o.w = f2bf((v.w - mean) * rstd * gv.w + bv.w);
  *(ushort4*)(y + row * 256 + c) = o;
}

// ---------------- scan: h[s] = a[s]*h[s-1] + bt[s], one lane per (batch, dim) -------------
__global__ __launch_bounds__(256)
void scan_kernel(const ushort* __restrict__ z, ushort* __restrict__ hs) {
  const long tid = (long)blockIdx.x * 256 + threadIdx.x;
  const long b = tid >> 6;
  const int d = tid & 63;
  const ushort* zb = z + b * (16 * 640);
  ushort* hb = hs + b * (16 * 64);
  float h = 0.f;
#pragma unroll
  for (int s = 0; s < 16; ++s) {
    float a  = bf2f(zb[s * 640 + d]);
    float bt = bf2f(zb[s * 640 + 64 + d]);
    h = fmaf(a, h, bt);
    hb[s * 64 + d] = f2bf(h);
  }
}

// ---------------- head: final LN + neighbor attention + MLP + log_softmax ----------------
__global__ __launch_bounds__(256)
void head_kernel(const float* __restrict__ x, const float* __restrict__ fg,
                 const float* __restrict__ fb, const float* __restrict__ attw,
                 const float* __restrict__ attb, const float* __restrict__ ow,
                 const float* __restrict__ ob, const float* __restrict__ cw,
                 const float* __restrict__ cb, float* __restrict__ out) {
  __shared__ float xf[16][256];
  __shared__ float lg[16], aw[16];
  __shared__ float vs[256], o1[128], lgc[40], lse[1];
  const int t = threadIdx.x, lane = t & 63, wid = t >> 6;
  const float* xb = x + (long)blockIdx.x * 16 * 256;
  (void)attb;  // constant shift, cancels in softmax

  for (int r = wid; r < 16; r += 4) {
    float4 v = *(const float4*)(xb + r * 256 + lane * 4);
    float s = v.x + v.y + v.z + v.w;
    float q = v.x * v.x + v.y * v.y + v.z * v.z + v.w * v.w;
#pragma unroll
    for (int off = 32; off > 0; off >>= 1) {
      s += __shfl_xor(s, off, 64);
      q += __shfl_xor(q, off, 64);
    }
    float mean = s * (1.f / 256.f);
    float rstd = rsqrtf(q * (1.f / 256.f) - mean * mean + 1e-5f);
    int c = lane * 4;
    xf[r][c + 0] = (v.x - mean) * rstd * fg[c + 0] + fb[c + 0];
    xf[r][c + 1] = (v.y - mean) * rstd * fg[c + 1] + fb[c + 1];
    xf[r][c + 2] = (v.z - mean) * rstd * fg[c + 2] + fb[c + 2];
    xf[r][c + 3] = (v.w - mean) * rstd * fg[c + 3] + fb[c + 3];
  }
  __syncthreads();

  for (int r = wid; r < 16; r += 4) {
    const float* wv = attw + (r == 0 ? 0 : 256);
    int c = lane * 4;
    float s = xf[r][c] * wv[c] + xf[r][c + 1] * wv[c + 1] +
              xf[r][c + 2] * wv[c + 2] + xf[r][c + 3] * wv[c + 3];
#pragma unroll
    for (int off = 32; off > 0; off >>= 1) s += __shfl_xor(s, off, 64);
    if (lane == 0) lg[r] = s;
  }
  __syncthreads();

  if (t == 0) {
    float mx = -1e30f;
    for (int s2 = 1; s2 < 16; ++s2) mx = fmaxf(mx, lg[s2]);
    float den = 0.f;
    for (int s2 = 1; s2 < 16; ++s2) { float e = expf(lg[s2] - mx); aw[s2] = e; den += e; }
    float inv = 1.f / den;
    for (int s2 = 1; s2 < 16; ++s2) aw[s2] *= inv;
  }
  __syncthreads();

  float vh = xf[0][t];
  for (int s2 = 1; s2 < 16; ++s2) vh += aw[s2] * xf[s2][t];
  vs[t] = vh;
  __syncthreads();

  if (t < 128) {
    float s = ob[t];
    const float* w = ow + t * 256;
    for (int h2 = 0; h2 < 256; ++h2) s += w[h2] * vs[h2];
    o1[t] = fmaxf(s, 0.f);
  }
  __syncthreads();

  if (t < 40) {
    float s = cb[t];
    const float* w = cw + t * 128;
    for (int j = 0; j < 128; ++j) s += w[j] * o1[j];
    lgc[t] = s;
  }
  __syncthreads();

  if (t == 0) {
    float mx = -1e30f;
    for (int c2 = 0; c2 < 40; ++c2) mx = fmaxf(mx, lgc[c2]);
    float den = 0.f;
    for (int c2 = 0; c2 < 40; ++c2) den += expf(lgc[c2] - mx);
    lse[0] = mx + logf(den);
  }
  __syncthreads();
  if (t < 40) out[(long)blockIdx.x * 40 + t] = lgc[t] - lse[0];
}

// ---------------- host ----------------
extern "C" void kernel_launch(void* const* d_in, const int* in_sizes, int n_in,
                              void* d_out, int out_size, void* d_ws, size_t ws_size,
                              hipStream_t stream) {
  const float* data   = (const float*)d_in[0];
  const float* in_w   = (const float*)d_in[1];
  const float* in_b   = (const float*)d_in[2];
  const float* norm_g = (const float*)d_in[3];
  const float* norm_b = (const float*)d_in[4];
  const float* A_w    = (const float*)d_in[5];
  const float* B_w    = (const float*)d_in[6];
  const float* C_w    = (const float*)d_in[7];
  const float* D_w    = (const float*)d_in[8];
  const float* D_b    = (const float*)d_in[9];
  const float* gate_w = (const float*)d_in[10];
  const float* gate_b = (const float*)d_in[11];
  const float* ffn_w1 = (const float*)d_in[12];
  const float* ffn_b1 = (const float*)d_in[13];
  const float* ffn_w2 = (const float*)d_in[14];
  const float* ffn_b2 = (const float*)d_in[15];
  const float* fln_g  = (const float*)d_in[16];
  const float* fln_b  = (const float*)d_in[17];
  const float* out_w  = (const float*)d_in[18];
  const float* out_b  = (const float*)d_in[19];
  const float* cls_w  = (const float*)d_in[20];
  const float* cls_b  = (const float*)d_in[21];
  const float* attn_w = (const float*)d_in[22];
  const float* attn_b = (const float*)d_in[23];
  (void)in_sizes; (void)n_in; (void)out_size; (void)ws_size;

  char* ws = (char*)d_ws;
  float*  x    = (float*)(ws + 0);            // 131072*256*4  = 134217728
  ushort* y    = (ushort*)(ws + 134217728);   // 131072*256*2  =  67108864
  ushort* z    = (ushort*)(ws + 201326592);   // 131072*640*2  = 167772160 (reused: datab, ffn1 t)
  ushort* hs   = (ushort*)(ws + 369098752);   // 131072*64*2   =  16777216
  ushort* wcat = (ushort*)(ws + 385875968);   // 6*640*256*2   =   1966080
  ushort* inwb = (ushort*)(ws + 387842048);   // 256*512*2     =    262144
  ushort* w1b  = (ushort*)(ws + 388104192);   // 6*512*256*2   =   1572864
  ushort* w2b  = (ushort*)(ws + 389677056);   // 6*256*512*2   =   1572864
  ushort* cwb  = (ushort*)(ws + 391249920);   // 6*256*64*2    =    196608
  ushort* datab = z;                          // 131072*512*2  = 134217728 (consumed before z written)

  cvt_kernel<<<512, 256, 0, stream>>>(in_w, inwb, 131072);
  cvt_kernel<<<3072, 256, 0, stream>>>(ffn_w1, w1b, 786432);
  cvt_kernel<<<3072, 256, 0, stream>>>(ffn_w2, w2b, 786432);
  cvt_kernel<<<384, 256, 0, stream>>>(C_w, cwb, 98304);
  build_wcat<<<3840, 256, 0, stream>>>(A_w, B_w, gate_w, D_w, wcat);
  cvt4_kernel<<<65536, 256, 0, stream>>>(data, datab, 16777216);

  // x = data @ in_w^T + in_b   (M=131072, K=512, N=256)
  gemm_bf16<512, 0><<<dim3(1024, 2), 256, 0, stream>>>(datab, inwb, in_b, nullptr, nullptr, x, 256);

  for (int l = 0; l < 6; ++l) {
    ln_kernel<<<32768, 256, 0, stream>>>(x, norm_g + l * 256, norm_b + l * 256, y);
    gemm_bf16<256, 1><<<dim3(1024, 5), 256, 0, stream>>>(
        y, wcat + (size_t)l * 640 * 256, gate_b + l * 256, D_b + l * 256, nullptr, z, 640);
    scan_kernel<<<2048, 256, 0, stream>>>(z, hs);
    gemm_bf16<64, 4><<<dim3(1024, 2), 256, 0, stream>>>(
        hs, cwb + (size_t)l * 256 * 64, nullptr, nullptr, z, x, 256);
    ln_kernel<<<32768, 256, 0, stream>>>(x, norm_g + l * 256, norm_b + l * 256, y);
    gemm_bf16<256, 2><<<dim3(1024, 4), 256, 0, stream>>>(
        y, w1b + (size_t)l * 512 * 256, ffn_b1 + l * 512, nullptr, nullptr, z, 512);
    gemm_bf16<512, 3><<<dim3(1024, 2), 256, 0, stream>>>(
        z, w2b + (size_t)l * 256 * 512, ffn_b2 + l * 256, nullptr, nullptr, x, 256);
  }

  head_kernel<<<8192, 256, 0, stream>>>(x, fln_g, fln_b, attn_w, attn_b,
                                        out_w, out_b, cls_w, cls_b, (float*)d_out);
}